// Round 4
// baseline (250.964 us; speedup 1.0000x reference)
//
#include <hip/hip_runtime.h>
#include <hip/hip_bf16.h>

#define N 4096
#define C 512

typedef __attribute__((ext_vector_type(8))) short bf16x8;
typedef __attribute__((ext_vector_type(8))) short s16x8;
typedef __attribute__((ext_vector_type(4))) float f32x4;
typedef __attribute__((ext_vector_type(16))) float f32x16;

__device__ inline float bf2f(__hip_bfloat16 h) { return __bfloat162float(h); }
__device__ inline float bfbits2f(unsigned short b) {
    union { unsigned u; float f; } c; c.u = ((unsigned)b) << 16; return c.f;
}

__device__ inline void gload16(const void* g, void* l) {
    __builtin_amdgcn_global_load_lds(
        (__attribute__((address_space(1))) void*)(g),
        (__attribute__((address_space(3))) void*)(l),
        16, 0, 0);
}

// ---------------- kernel 1: row L2-normalize + bf16 hi/lo split ----------------
// One wave per row: shuffle-only reduction, 16B stores. 4 waves/block.
__global__ __launch_bounds__(256) void k_norm_split(
    const float* __restrict__ s0, const float* __restrict__ s1f,
    const float* __restrict__ s2f, const float* __restrict__ s3,
    __hip_bfloat16* __restrict__ ws_hi0, long mat_stride) // stride in bf16 elems
{
    const int lane = threadIdx.x & 63;
    const int w = threadIdx.x >> 6;
    const int grow = blockIdx.x * 4 + w;       // 0..16383
    const int m = grow >> 12;
    const int row = grow & 4095;
    const float* src = (m == 0) ? s0 : (m == 1) ? s1f : (m == 2) ? s2f : s3;
    __hip_bfloat16* hi = ws_hi0 + (long)m * mat_stride;
    __hip_bfloat16* lo = hi + (long)N * C;

    const float4* r4 = (const float4*)(src + (size_t)row * C);
    float4 x0 = r4[lane * 2];
    float4 x1 = r4[lane * 2 + 1];
    float ss = x0.x*x0.x + x0.y*x0.y + x0.z*x0.z + x0.w*x0.w
             + x1.x*x1.x + x1.y*x1.y + x1.z*x1.z + x1.w*x1.w;
    for (int o = 1; o < 64; o <<= 1) ss += __shfl_xor(ss, o);
    float scale = 1.0f / fmaxf(sqrtf(ss), 1e-12f);

    float y[8] = { x0.x*scale, x0.y*scale, x0.z*scale, x0.w*scale,
                   x1.x*scale, x1.y*scale, x1.z*scale, x1.w*scale };
    __hip_bfloat16 hv[8], lv[8];
    for (int e = 0; e < 8; e++) {
        hv[e] = __float2bfloat16(y[e]);
        lv[e] = __float2bfloat16(y[e] - bf2f(hv[e]));
    }
    size_t base = (size_t)row * C + lane * 8;
    *(s16x8*)(hi + base) = *(s16x8*)hv;
    *(s16x8*)(lo + base) = *(s16x8*)lv;
}

// ---------------- kernel 2: both diagonals, vectorized ----------------
__global__ __launch_bounds__(256) void k_diag(
    const unsigned short* __restrict__ h0, const unsigned short* __restrict__ l0,
    const unsigned short* __restrict__ h1, const unsigned short* __restrict__ l1,
    const unsigned short* __restrict__ h2, const unsigned short* __restrict__ l2,
    const unsigned short* __restrict__ h3, const unsigned short* __restrict__ l3,
    float* __restrict__ dv, float* __restrict__ dt)
{
    const int lane = threadIdx.x & 63;
    const int w = threadIdx.x >> 6;
    const int row = blockIdx.x * 4 + w;
    const int z = blockIdx.y;
    const unsigned short* ah = z ? h1 : h0;
    const unsigned short* al = z ? l1 : l0;
    const unsigned short* bh = z ? h2 : h3;
    const unsigned short* bl = z ? l2 : l3;
    float* dout = z ? dt : dv;

    size_t base = (size_t)row * C + lane * 8;
    s16x8 xh = *(const s16x8*)(ah + base);
    s16x8 xl = *(const s16x8*)(al + base);
    s16x8 yh = *(const s16x8*)(bh + base);
    s16x8 yl = *(const s16x8*)(bl + base);
    float s = 0.f;
    for (int e = 0; e < 8; e++) {
        float a = bfbits2f((unsigned short)xh[e]);
        float b = bfbits2f((unsigned short)xl[e]);
        float c = bfbits2f((unsigned short)yh[e]);
        float d = bfbits2f((unsigned short)yl[e]);
        s += a * c + a * d + b * c;
    }
    for (int o = 1; o < 64; o <<= 1) s += __shfl_xor(s, o);
    if (lane == 0) dout[row] = s;
}

// ---------------- kernel 3: fused split-GEMM + epilogue (32x32x16 MFMA) -------
// C-tile 128x128, BK=32, 4 waves (2x2), each wave 2x2 tiles of 32x32.
// 3 MFMA passes per tile pair (hi*hi + hi*lo + lo*hi).
// Epilogue partials row-major: pe[row*32 + colblock].
__global__ __launch_bounds__(256) void k_gemm(
    const __hip_bfloat16* __restrict__ h0, const __hip_bfloat16* __restrict__ l0,
    const __hip_bfloat16* __restrict__ h1, const __hip_bfloat16* __restrict__ l1,
    const __hip_bfloat16* __restrict__ h2, const __hip_bfloat16* __restrict__ l2,
    const __hip_bfloat16* __restrict__ h3, const __hip_bfloat16* __restrict__ l3,
    const float* __restrict__ dv, const float* __restrict__ dt,
    float* __restrict__ pev, float* __restrict__ pet,
    float* __restrict__ pcv, float* __restrict__ pct)
{
    __shared__ __align__(16) __hip_bfloat16 sA[2][128][32];
    __shared__ __align__(16) __hip_bfloat16 sB[2][128][32];
    __shared__ float sdiag[128];
    __shared__ float sred[128][2][2];

    const int z = blockIdx.z;
    const __hip_bfloat16* Ah = z ? h1 : h0;
    const __hip_bfloat16* Al = z ? l1 : l0;
    const __hip_bfloat16* Bh = z ? h2 : h3;
    const __hip_bfloat16* Bl = z ? l2 : l3;
    const float* diag = z ? dt : dv;
    float* pe = z ? pet : pev;
    float* pc = z ? pct : pcv;

    const int tid = threadIdx.x;
    const int lane = tid & 63;
    const int w = tid >> 6;
    const int wy = w >> 1, wx = w & 1;
    const int bm = blockIdx.x * 128;
    const int bn = blockIdx.y * 128;

    if (tid < 128) sdiag[tid] = diag[bm + tid];

    f32x16 acc[2][2];
    for (int i = 0; i < 2; i++)
        for (int j = 0; j < 2; j++)
            for (int e = 0; e < 16; e++) acc[i][j][e] = 0.f;

    const int srow = lane >> 2;        // 0..15
    const int scol = (lane & 3) * 8;   // bf16 elems
    const int mrow = lane & 31;        // A/B fragment row (m / n)
    const int khalf = (lane >> 5) * 8; // k offset within 16-wide k-step

    for (int k0 = 0; k0 < C; k0 += 32) {
        for (int half = 0; half < 2; half++) {
            int rr = w * 16 + half * 64 + srow;
            size_t ga = (size_t)(bm + rr) * C + k0 + scol;
            size_t gb = (size_t)(bn + rr) * C + k0 + scol;
            gload16(Ah + ga, &sA[0][rr][scol]);
            gload16(Al + ga, &sA[1][rr][scol]);
            gload16(Bh + gb, &sB[0][rr][scol]);
            gload16(Bl + gb, &sB[1][rr][scol]);
        }
        __syncthreads();

        for (int ks = 0; ks < 2; ks++) {           // two K=16 steps
            const int kk = ks * 16 + khalf;
            bf16x8 a_h[2], a_l[2], b_h[2], b_l[2];
            for (int i = 0; i < 2; i++) {
                a_h[i] = *(const bf16x8*)&sA[0][wy * 64 + i * 32 + mrow][kk];
                a_l[i] = *(const bf16x8*)&sA[1][wy * 64 + i * 32 + mrow][kk];
                b_h[i] = *(const bf16x8*)&sB[0][wx * 64 + i * 32 + mrow][kk];
                b_l[i] = *(const bf16x8*)&sB[1][wx * 64 + i * 32 + mrow][kk];
            }
            for (int i = 0; i < 2; i++)
                for (int j = 0; j < 2; j++)
                    acc[i][j] = __builtin_amdgcn_mfma_f32_32x32x16_bf16(a_h[i], b_h[j], acc[i][j], 0, 0, 0);
            for (int i = 0; i < 2; i++)
                for (int j = 0; j < 2; j++)
                    acc[i][j] = __builtin_amdgcn_mfma_f32_32x32x16_bf16(a_h[i], b_l[j], acc[i][j], 0, 0, 0);
            for (int i = 0; i < 2; i++)
                for (int j = 0; j < 2; j++)
                    acc[i][j] = __builtin_amdgcn_mfma_f32_32x32x16_bf16(a_l[i], b_h[j], acc[i][j], 0, 0, 0);
        }
        __syncthreads();
    }

    // epilogue: 32x32 C/D layout col=lane&31, row=(reg&3)+8*(reg>>2)+4*(lane>>5)
    const int colr = lane & 31;
    const int halfg = lane >> 5;
    for (int i = 0; i < 2; i++) {
        for (int reg = 0; reg < 16; reg++) {
            int rloc = wy * 64 + i * 32 + (reg & 3) + 8 * (reg >> 2) + 4 * halfg;
            int grow = bm + rloc;
            float d = sdiag[rloc];
            float e = 0.f, c = 0.f;
            for (int j = 0; j < 2; j++) {
                float s = acc[i][j][reg];
                int gcol = bn + wx * 64 + j * 32 + colr;
                e += __expf(10.f * s - 10.f);
                if (s > d && gcol != grow) c += 1.f;
            }
            for (int o = 1; o < 32; o <<= 1) {
                e += __shfl_xor(e, o);
                c += __shfl_xor(c, o);
            }
            if (colr == 0) { sred[rloc][wx][0] = e; sred[rloc][wx][1] = c; }
        }
    }
    __syncthreads();
    if (tid < 128) {
        size_t idx = (size_t)(bm + tid) * 32 + blockIdx.y;
        pe[idx] = sred[tid][0][0] + sred[tid][1][0];
        pc[idx] = sred[tid][0][1] + sred[tid][1][1];
    }
}

// ---------------- kernel 4: per-column sum/sumsq partials, vectorized ---------
// grid (32 chunks x 4 mats), 256 threads. Thread t: col-group t&63 (8 cols),
// row-slice t>>6 (32 rows). Fully-coalesced 16B loads.
__global__ __launch_bounds__(256) void k_stdp(
    const __hip_bfloat16* __restrict__ ws_hi0, long mat_stride,
    float* __restrict__ s1, float* __restrict__ s2)
{
    const int t = threadIdx.x;
    const int colg = t & 63;
    const int slice = t >> 6;
    const int chunk = blockIdx.x;    // 0..31, 128 rows each
    const int m = blockIdx.y;
    const unsigned short* hi = (const unsigned short*)(ws_hi0 + (long)m * mat_stride);
    const unsigned short* lo = hi + (size_t)N * C;

    float a[8], b[8];
    for (int e = 0; e < 8; e++) { a[e] = 0.f; b[e] = 0.f; }
    const int row0 = chunk * 128 + slice * 32;
    for (int r = 0; r < 32; r++) {
        size_t addr = (size_t)(row0 + r) * C + colg * 8;
        s16x8 h8 = *(const s16x8*)(hi + addr);
        s16x8 l8 = *(const s16x8*)(lo + addr);
        for (int e = 0; e < 8; e++) {
            float y = bfbits2f((unsigned short)h8[e]) + bfbits2f((unsigned short)l8[e]);
            a[e] += y;
            b[e] += y * y;
        }
    }
    __shared__ float sa[4][512];
    __shared__ float sb[4][512];
    for (int e = 0; e < 8; e++) {
        sa[slice][colg * 8 + e] = a[e];
        sb[slice][colg * 8 + e] = b[e];
    }
    __syncthreads();
    for (int c = t; c < 512; c += 256) {
        float A = sa[0][c] + sa[1][c] + sa[2][c] + sa[3][c];
        float B = sb[0][c] + sb[1][c] + sb[2][c] + sb[3][c];
        size_t idx = ((size_t)m * 32 + chunk) * 512 + c;
        s1[idx] = A;
        s2[idx] = B;
    }
}

// ---------------- kernel 5a: row reduction, 64 blocks x 64 threads -------------
__global__ __launch_bounds__(64) void k_rowred(
    const float* __restrict__ dv, const float* __restrict__ dt,
    const float* __restrict__ pev, const float* __restrict__ pet,
    const float* __restrict__ pcv, const float* __restrict__ pct,
    float* __restrict__ partials)
{
    const int lane = threadIdx.x;
    const int row = blockIdx.x * 64 + lane;

    float se = 0.f, pv = 0.f, pt = 0.f;
    const float4* e4v = (const float4*)(pev + (size_t)row * 32);
    const float4* e4t = (const float4*)(pet + (size_t)row * 32);
    const float4* c4v = (const float4*)(pcv + (size_t)row * 32);
    const float4* c4t = (const float4*)(pct + (size_t)row * 32);
    for (int q = 0; q < 8; q++) {
        float4 a = e4v[q], b = e4t[q], c = c4v[q], d = c4t[q];
        se += a.x + a.y + a.z + a.w + b.x + b.y + b.z + b.w;
        pv += c.x + c.y + c.z + c.w;
        pt += d.x + d.y + d.z + d.w;
    }

    float vals[10];
    vals[0] = logf(se) + 10.f;
    vals[1] = (pv < 0.5f) ? 1.f : 0.f;
    vals[2] = (pv < 4.5f) ? 1.f : 0.f;
    vals[3] = (pv < 9.5f) ? 1.f : 0.f;
    vals[4] = pv;
    vals[5] = (pt < 0.5f) ? 1.f : 0.f;
    vals[6] = (pt < 4.5f) ? 1.f : 0.f;
    vals[7] = (pt < 9.5f) ? 1.f : 0.f;
    vals[8] = pt;
    vals[9] = __expf(10.f * dv[row] - 10.f) + __expf(10.f * dt[row] - 10.f);

    for (int k = 0; k < 10; k++) {
        float v = vals[k];
        for (int o = 1; o < 64; o <<= 1) v += __shfl_xor(v, o);
        if (lane == k) partials[(size_t)blockIdx.x * 10 + k] = v;
    }
}

// ---------------- kernel 5b: per-column std, 32 blocks x 64 threads ------------
__global__ __launch_bounds__(64) void k_colstd(
    const float* __restrict__ s1, const float* __restrict__ s2,
    float* __restrict__ stdpart)
{
    const int lane = threadIdx.x;
    const int m = blockIdx.x >> 3;
    const int col = (blockIdx.x & 7) * 64 + lane;
    float a = 0.f, b = 0.f;
    for (int ch = 0; ch < 32; ch++) {
        size_t idx = ((size_t)m * 32 + ch) * 512 + col;
        a += s1[idx];
        b += s2[idx];
    }
    float var = (b - a * a * (1.f / N)) * (1.f / (N - 1));
    float sd = sqrtf(fmaxf(var, 0.f));
    for (int o = 1; o < 64; o <<= 1) sd += __shfl_xor(sd, o);
    if (lane == 0) stdpart[blockIdx.x] = sd;
}

// ---------------- kernel 5c: tiny final combine --------------------------------
__global__ __launch_bounds__(64) void k_final2(
    const float* __restrict__ partials,   // [64][10]
    const float* __restrict__ stdpart,    // [32] (8 per matrix)
    float* __restrict__ out)
{
    const int lane = threadIdx.x;
    float v = 0.f;
    if (lane < 10) {
        for (int b = 0; b < 64; b++) v += partials[b * 10 + lane];
    }
    __shared__ float g[10];
    __shared__ float stds[4];
    if (lane < 10) g[lane] = v;
    if (lane < 4) {
        float s = 0.f;
        for (int i = 0; i < 8; i++) s += stdpart[lane * 8 + i];
        stds[lane] = s * (1.f / 512.f);
    }
    __syncthreads();
    if (lane == 0) {
        const float invN = 1.f / N;
        float nominator = logf(g[9]) + 10.f;
        out[0]  = g[0] * invN - nominator;
        out[1]  = stds[0];
        out[2]  = stds[1];
        out[3]  = stds[2];
        out[4]  = stds[3];
        out[5]  = g[1] * invN;
        out[6]  = g[2] * invN;
        out[7]  = g[3] * invN;
        out[8]  = g[4] * invN;
        out[9]  = g[5] * invN;
        out[10] = g[6] * invN;
        out[11] = g[7] * invN;
        out[12] = g[8] * invN;
    }
}

extern "C" void kernel_launch(void* const* d_in, const int* in_sizes, int n_in,
                              void* d_out, int out_size, void* d_ws, size_t ws_size,
                              hipStream_t stream)
{
    char* p = (char*)d_ws;
    const size_t NE = (size_t)N * C;           // 2,097,152 elems
    const long mat_stride = 2 * NE;            // hi + lo, in bf16 elems
    __hip_bfloat16* hiA[4];
    __hip_bfloat16* loA[4];
    for (int m = 0; m < 4; m++) {
        hiA[m] = (__hip_bfloat16*)p; p += NE * 2;
        loA[m] = (__hip_bfloat16*)p; p += NE * 2;
    }
    float* dv  = (float*)p; p += N * 4;
    float* dt  = (float*)p; p += N * 4;
    float* pev = (float*)p; p += 32 * N * 4;
    float* pet = (float*)p; p += 32 * N * 4;
    float* pcv = (float*)p; p += 32 * N * 4;
    float* pct = (float*)p; p += 32 * N * 4;
    float* s1  = (float*)p; p += 4 * 32 * 512 * 4;
    float* s2  = (float*)p; p += 4 * 32 * 512 * 4;
    float* partials = (float*)p; p += 64 * 10 * 4;
    float* stdpart  = (float*)p; p += 32 * 4;

    // 1. normalize + split (all 4 matrices, one wave per row)
    k_norm_split<<<dim3(4 * N / 4), 256, 0, stream>>>(
        (const float*)d_in[0], (const float*)d_in[1],
        (const float*)d_in[2], (const float*)d_in[3],
        hiA[0], mat_stride);

    // 2. both diagonals in one dispatch
    k_diag<<<dim3(N / 4, 2), 256, 0, stream>>>(
        (const unsigned short*)hiA[0], (const unsigned short*)loA[0],
        (const unsigned short*)hiA[1], (const unsigned short*)loA[1],
        (const unsigned short*)hiA[2], (const unsigned short*)loA[2],
        (const unsigned short*)hiA[3], (const unsigned short*)loA[3],
        dv, dt);

    // 3. both fused GEMMs in one dispatch (z selects)
    k_gemm<<<dim3(32, 32, 2), 256, 0, stream>>>(
        hiA[0], loA[0], hiA[1], loA[1], hiA[2], loA[2], hiA[3], loA[3],
        dv, dt, pev, pet, pcv, pct);

    // 4. std partials: 32 chunks x 4 matrices, vectorized
    k_stdp<<<dim3(32, 4), 256, 0, stream>>>(hiA[0], mat_stride, s1, s2);

    // 5. parallel finalization
    k_rowred<<<dim3(64), 64, 0, stream>>>(dv, dt, pev, pet, pcv, pct, partials);
    k_colstd<<<dim3(32), 64, 0, stream>>>(s1, s2, stdpart);
    k_final2<<<dim3(1), 64, 0, stream>>>(partials, stdpart, (float*)d_out);
}

// Round 5
// 217.008 us; speedup vs baseline: 1.1565x; 1.1565x over previous
//
#include <hip/hip_runtime.h>
#include <hip/hip_bf16.h>

#define N 4096
#define C 512

typedef __attribute__((ext_vector_type(8))) short bf16x8;
typedef __attribute__((ext_vector_type(8))) short s16x8;
typedef __attribute__((ext_vector_type(4))) float f32x4;

__device__ inline float bf2f(__hip_bfloat16 h) { return __bfloat162float(h); }
__device__ inline float bfbits2f(unsigned short b) {
    union { unsigned u; float f; } c; c.u = ((unsigned)b) << 16; return c.f;
}

__device__ inline void gload16(const void* g, void* l) {
    __builtin_amdgcn_global_load_lds(
        (__attribute__((address_space(1))) void*)(g),
        (__attribute__((address_space(3))) void*)(l),
        16, 0, 0);
}

// ================= kernel 1: prep (norm+split | diag | std partials) ==========
// blocks [0,4096): row L2-normalize + bf16 hi/lo split (1 wave per row)
// blocks [4096,6144): diagonals from fp32 (self-normalizing)
// blocks [6144,6272): per-column sum/sumsq partials from fp32 (self-normalizing)
// block 0 also zeroes the k_fin completion counter.
__global__ __launch_bounds__(256) void k_prep(
    const float* __restrict__ s0, const float* __restrict__ s1f,
    const float* __restrict__ s2f, const float* __restrict__ s3,
    __hip_bfloat16* __restrict__ ws_hi0, long mat_stride,
    float* __restrict__ dv, float* __restrict__ dt,
    float* __restrict__ st1, float* __restrict__ st2,
    unsigned int* __restrict__ counter)
{
    __shared__ float sa[4][512];
    __shared__ float sb[4][512];

    const int b = blockIdx.x;
    const int tid = threadIdx.x;
    const int lane = tid & 63;
    const int w = tid >> 6;

    if (b == 0 && tid == 0) *counter = 0;

    if (b < 4096) {
        // ---- normalize + split ----
        const int grow = b * 4 + w;
        const int m = grow >> 12;
        const int row = grow & 4095;
        const float* src = (m == 0) ? s0 : (m == 1) ? s1f : (m == 2) ? s2f : s3;
        __hip_bfloat16* hi = ws_hi0 + (long)m * mat_stride;
        __hip_bfloat16* lo = hi + (long)N * C;

        const float4* r4 = (const float4*)(src + (size_t)row * C);
        float4 x0 = r4[lane * 2];
        float4 x1 = r4[lane * 2 + 1];
        float ss = x0.x*x0.x + x0.y*x0.y + x0.z*x0.z + x0.w*x0.w
                 + x1.x*x1.x + x1.y*x1.y + x1.z*x1.z + x1.w*x1.w;
        for (int o = 1; o < 64; o <<= 1) ss += __shfl_xor(ss, o);
        float scale = 1.0f / fmaxf(sqrtf(ss), 1e-12f);
        float y[8] = { x0.x*scale, x0.y*scale, x0.z*scale, x0.w*scale,
                       x1.x*scale, x1.y*scale, x1.z*scale, x1.w*scale };
        __hip_bfloat16 hv[8], lv[8];
        for (int e = 0; e < 8; e++) {
            hv[e] = __float2bfloat16(y[e]);
            lv[e] = __float2bfloat16(y[e] - bf2f(hv[e]));
        }
        size_t base = (size_t)row * C + lane * 8;
        *(s16x8*)(hi + base) = *(s16x8*)hv;
        *(s16x8*)(lo + base) = *(s16x8*)lv;
    } else if (b < 6144) {
        // ---- diagonals: dv = diag(vn.ptn^T) (z=0), dt = diag(tn.pvn^T) (z=1) --
        const int idx = b - 4096;            // 0..2047
        const int z = idx >> 10;
        const int row = (idx & 1023) * 4 + w;
        const float* A = z ? s1f : s0;       // t : v
        const float* B = z ? s2f : s3;       // pv : pt
        float* dout = z ? dt : dv;

        const float4* a4 = (const float4*)(A + (size_t)row * C);
        const float4* b4 = (const float4*)(B + (size_t)row * C);
        float4 a0 = a4[lane * 2], a1 = a4[lane * 2 + 1];
        float4 b0 = b4[lane * 2], b1 = b4[lane * 2 + 1];
        float ssa = a0.x*a0.x + a0.y*a0.y + a0.z*a0.z + a0.w*a0.w
                  + a1.x*a1.x + a1.y*a1.y + a1.z*a1.z + a1.w*a1.w;
        float ssb = b0.x*b0.x + b0.y*b0.y + b0.z*b0.z + b0.w*b0.w
                  + b1.x*b1.x + b1.y*b1.y + b1.z*b1.z + b1.w*b1.w;
        float dot = a0.x*b0.x + a0.y*b0.y + a0.z*b0.z + a0.w*b0.w
                  + a1.x*b1.x + a1.y*b1.y + a1.z*b1.z + a1.w*b1.w;
        for (int o = 1; o < 64; o <<= 1) {
            ssa += __shfl_xor(ssa, o);
            ssb += __shfl_xor(ssb, o);
            dot += __shfl_xor(dot, o);
        }
        if (lane == 0)
            dout[row] = dot / (fmaxf(sqrtf(ssa), 1e-12f) * fmaxf(sqrtf(ssb), 1e-12f));
    } else {
        // ---- std partials: 32 chunks x 4 mats, 128 rows/chunk ----
        const int idx = b - 6144;            // 0..127
        const int m = idx >> 5;
        const int chunk = idx & 31;
        const float* src = (m == 0) ? s0 : (m == 1) ? s1f : (m == 2) ? s2f : s3;
        const int slice = w;                 // 4 slices x 32 rows

        float a[8], q[8];
        for (int e = 0; e < 8; e++) { a[e] = 0.f; q[e] = 0.f; }
        const int row0 = chunk * 128 + slice * 32;
        for (int r = 0; r < 32; r++) {
            const float4* r4 = (const float4*)(src + (size_t)(row0 + r) * C);
            float4 x0 = r4[lane * 2];
            float4 x1 = r4[lane * 2 + 1];
            float ss = x0.x*x0.x + x0.y*x0.y + x0.z*x0.z + x0.w*x0.w
                     + x1.x*x1.x + x1.y*x1.y + x1.z*x1.z + x1.w*x1.w;
            for (int o = 1; o < 64; o <<= 1) ss += __shfl_xor(ss, o);
            float scale = 1.0f / fmaxf(sqrtf(ss), 1e-12f);
            float y[8] = { x0.x*scale, x0.y*scale, x0.z*scale, x0.w*scale,
                           x1.x*scale, x1.y*scale, x1.z*scale, x1.w*scale };
            for (int e = 0; e < 8; e++) { a[e] += y[e]; q[e] += y[e] * y[e]; }
        }
        for (int e = 0; e < 8; e++) {
            sa[slice][lane * 8 + e] = a[e];
            sb[slice][lane * 8 + e] = q[e];
        }
        __syncthreads();
        for (int c = tid; c < 512; c += 256) {
            float A = sa[0][c] + sa[1][c] + sa[2][c] + sa[3][c];
            float B = sb[0][c] + sb[1][c] + sb[2][c] + sb[3][c];
            size_t o = ((size_t)m * 32 + chunk) * 512 + c;
            st1[o] = A;
            st2[o] = B;
        }
    }
}

// ================= kernel 2: fused split-GEMM + epilogue (16x16x32) ===========
// C-tile 128x128, BK=32, 4 waves (2x2), 3 MFMA per frag pair (hi*hi+hi*lo+lo*hi).
// XOR k-block swizzle: physical slot (r,c') holds logical (r, c' ^ ((r>>1)&3)).
// Staging stays contiguous (lds = base + lane*16); the GLOBAL k-col is permuted.
__global__ __launch_bounds__(256) void k_gemm(
    const __hip_bfloat16* __restrict__ h0, const __hip_bfloat16* __restrict__ l0,
    const __hip_bfloat16* __restrict__ h1, const __hip_bfloat16* __restrict__ l1,
    const __hip_bfloat16* __restrict__ h2, const __hip_bfloat16* __restrict__ l2,
    const __hip_bfloat16* __restrict__ h3, const __hip_bfloat16* __restrict__ l3,
    const float* __restrict__ dv, const float* __restrict__ dt,
    float* __restrict__ pev, float* __restrict__ pet,
    float* __restrict__ pcv, float* __restrict__ pct)
{
    __shared__ __align__(16) __hip_bfloat16 sA[2][128][32];
    __shared__ __align__(16) __hip_bfloat16 sB[2][128][32];
    __shared__ float sdiag[128];
    __shared__ float sred[128][2][2];

    const int z = blockIdx.z;
    const __hip_bfloat16* Ah = z ? h1 : h0;
    const __hip_bfloat16* Al = z ? l1 : l0;
    const __hip_bfloat16* Bh = z ? h2 : h3;
    const __hip_bfloat16* Bl = z ? l2 : l3;
    const float* diag = z ? dt : dv;
    float* pe = z ? pet : pev;
    float* pc = z ? pct : pcv;

    const int tid = threadIdx.x;
    const int lane = tid & 63;
    const int w = tid >> 6;
    const int wy = w >> 1, wx = w & 1;
    const int bm = blockIdx.x * 128;
    const int bn = blockIdx.y * 128;

    if (tid < 128) sdiag[tid] = diag[bm + tid];

    f32x4 acc[4][4];
    for (int i = 0; i < 4; i++)
        for (int j = 0; j < 4; j++)
            acc[i][j] = (f32x4){0.f, 0.f, 0.f, 0.f};

    const int srow = lane >> 2;                               // 0..15
    const int lcol = (lane & 3) * 8;                          // LDS dst (natural)
    const int scolg = (((lane & 3) ^ ((lane >> 3) & 3))) * 8; // swizzled global k
    const int fr = lane & 15;
    const int pcs = ((lane >> 4) ^ ((fr >> 1) & 3)) * 8;      // swizzled read k

    for (int k0 = 0; k0 < C; k0 += 32) {
        for (int half = 0; half < 2; half++) {
            int rr = w * 16 + half * 64 + srow;
            size_t ga = (size_t)(bm + rr) * C + k0 + scolg;
            size_t gb = (size_t)(bn + rr) * C + k0 + scolg;
            gload16(Ah + ga, &sA[0][rr][lcol]);
            gload16(Al + ga, &sA[1][rr][lcol]);
            gload16(Bh + gb, &sB[0][rr][lcol]);
            gload16(Bl + gb, &sB[1][rr][lcol]);
        }
        __syncthreads();

        bf16x8 a_h[4], a_l[4], b_h[4], b_l[4];
        for (int i = 0; i < 4; i++) {
            a_h[i] = *(const bf16x8*)&sA[0][wy * 64 + i * 16 + fr][pcs];
            a_l[i] = *(const bf16x8*)&sA[1][wy * 64 + i * 16 + fr][pcs];
            b_h[i] = *(const bf16x8*)&sB[0][wx * 64 + i * 16 + fr][pcs];
            b_l[i] = *(const bf16x8*)&sB[1][wx * 64 + i * 16 + fr][pcs];
        }
        for (int i = 0; i < 4; i++)
            for (int j = 0; j < 4; j++) {
                acc[i][j] = __builtin_amdgcn_mfma_f32_16x16x32_bf16(a_h[i], b_h[j], acc[i][j], 0, 0, 0);
                acc[i][j] = __builtin_amdgcn_mfma_f32_16x16x32_bf16(a_h[i], b_l[j], acc[i][j], 0, 0, 0);
                acc[i][j] = __builtin_amdgcn_mfma_f32_16x16x32_bf16(a_l[i], b_h[j], acc[i][j], 0, 0, 0);
            }
        __syncthreads();
    }

    // epilogue: C/D layout row=(lane>>4)*4+reg, col=lane&15
    const int quad = lane >> 4;
    for (int i = 0; i < 4; i++) {
        for (int reg = 0; reg < 4; reg++) {
            int rloc = wy * 64 + i * 16 + quad * 4 + reg;
            int grow = bm + rloc;
            float d = sdiag[rloc];
            float e = 0.f, c = 0.f;
            for (int j = 0; j < 4; j++) {
                float s = acc[i][j][reg];
                int gcol = bn + wx * 64 + j * 16 + fr;
                e += __expf(10.f * s - 10.f);
                if (s > d && gcol != grow) c += 1.f;
            }
            for (int o = 1; o < 16; o <<= 1) {
                e += __shfl_xor(e, o);
                c += __shfl_xor(c, o);
            }
            if (fr == 0) { sred[rloc][wx][0] = e; sred[rloc][wx][1] = c; }
        }
    }
    __syncthreads();
    if (tid < 128) {
        size_t idx = (size_t)(bm + tid) * 32 + blockIdx.y;
        pe[idx] = sred[tid][0][0] + sred[tid][1][0];
        pc[idx] = sred[tid][0][1] + sred[tid][1][1];
    }
}

// ================= kernel 3: finalization (rowred | colstd | last-block) ======
// blocks [0,64): row reduction -> partials[b][10]
// blocks [64,96): per-column std -> stdpart[b-64]
// last block to finish (device-scope atomic) combines everything -> out[13].
__global__ __launch_bounds__(64) void k_fin(
    const float* __restrict__ dv, const float* __restrict__ dt,
    const float* __restrict__ pev, const float* __restrict__ pet,
    const float* __restrict__ pcv, const float* __restrict__ pct,
    const float* __restrict__ st1, const float* __restrict__ st2,
    float* __restrict__ partials, float* __restrict__ stdpart,
    unsigned int* __restrict__ counter, float* __restrict__ out)
{
    const int b = blockIdx.x;
    const int lane = threadIdx.x;

    if (b < 64) {
        const int row = b * 64 + lane;
        float se = 0.f, pv = 0.f, pt = 0.f;
        const float4* e4v = (const float4*)(pev + (size_t)row * 32);
        const float4* e4t = (const float4*)(pet + (size_t)row * 32);
        const float4* c4v = (const float4*)(pcv + (size_t)row * 32);
        const float4* c4t = (const float4*)(pct + (size_t)row * 32);
        for (int q = 0; q < 8; q++) {
            float4 a = e4v[q], bb = e4t[q], c = c4v[q], d = c4t[q];
            se += a.x + a.y + a.z + a.w + bb.x + bb.y + bb.z + bb.w;
            pv += c.x + c.y + c.z + c.w;
            pt += d.x + d.y + d.z + d.w;
        }
        float vals[10];
        vals[0] = logf(se) + 10.f;
        vals[1] = (pv < 0.5f) ? 1.f : 0.f;
        vals[2] = (pv < 4.5f) ? 1.f : 0.f;
        vals[3] = (pv < 9.5f) ? 1.f : 0.f;
        vals[4] = pv;
        vals[5] = (pt < 0.5f) ? 1.f : 0.f;
        vals[6] = (pt < 4.5f) ? 1.f : 0.f;
        vals[7] = (pt < 9.5f) ? 1.f : 0.f;
        vals[8] = pt;
        vals[9] = __expf(10.f * dv[row] - 10.f) + __expf(10.f * dt[row] - 10.f);
        for (int k = 0; k < 10; k++) {
            float v = vals[k];
            for (int o = 1; o < 64; o <<= 1) v += __shfl_xor(v, o);
            if (lane == k) partials[(size_t)b * 10 + k] = v;
        }
    } else {
        const int idx = b - 64;              // 0..31
        const int m = idx >> 3;
        const int col = (idx & 7) * 64 + lane;
        float a = 0.f, q = 0.f;
        for (int ch = 0; ch < 32; ch++) {
            size_t o = ((size_t)m * 32 + ch) * 512 + col;
            a += st1[o];
            q += st2[o];
        }
        float var = (q - a * a * (1.f / N)) * (1.f / (N - 1));
        float sd = sqrtf(fmaxf(var, 0.f));
        for (int o = 1; o < 64; o <<= 1) sd += __shfl_xor(sd, o);
        if (lane == 0) stdpart[idx] = sd;
    }

    __syncthreads();
    __shared__ unsigned int s_old;
    if (lane == 0) {
        __threadfence();                     // release our partial writes
        s_old = atomicAdd(counter, 1u);
    }
    __syncthreads();
    if (s_old != 95) return;
    __threadfence();                         // acquire everyone's writes

    // ---- last block: final combine (deterministic order) ----
    float v = 0.f;
    if (lane < 10) {
        for (int k = 0; k < 64; k++) v += partials[k * 10 + lane];
    }
    __shared__ float g[10];
    __shared__ float stds[4];
    if (lane < 10) g[lane] = v;
    if (lane < 4) {
        float s = 0.f;
        for (int i = 0; i < 8; i++) s += stdpart[lane * 8 + i];
        stds[lane] = s * (1.f / 512.f);
    }
    __syncthreads();
    if (lane == 0) {
        const float invN = 1.f / N;
        float nominator = logf(g[9]) + 10.f;
        out[0]  = g[0] * invN - nominator;
        out[1]  = stds[0];
        out[2]  = stds[1];
        out[3]  = stds[2];
        out[4]  = stds[3];
        out[5]  = g[1] * invN;
        out[6]  = g[2] * invN;
        out[7]  = g[3] * invN;
        out[8]  = g[4] * invN;
        out[9]  = g[5] * invN;
        out[10] = g[6] * invN;
        out[11] = g[7] * invN;
        out[12] = g[8] * invN;
    }
}

extern "C" void kernel_launch(void* const* d_in, const int* in_sizes, int n_in,
                              void* d_out, int out_size, void* d_ws, size_t ws_size,
                              hipStream_t stream)
{
    char* p = (char*)d_ws;
    const size_t NE = (size_t)N * C;           // 2,097,152 elems
    const long mat_stride = 2 * NE;            // hi + lo, in bf16 elems
    __hip_bfloat16* hiA[4];
    __hip_bfloat16* loA[4];
    for (int m = 0; m < 4; m++) {
        hiA[m] = (__hip_bfloat16*)p; p += NE * 2;
        loA[m] = (__hip_bfloat16*)p; p += NE * 2;
    }
    float* dv  = (float*)p; p += N * 4;
    float* dt  = (float*)p; p += N * 4;
    float* pev = (float*)p; p += 32 * N * 4;
    float* pet = (float*)p; p += 32 * N * 4;
    float* pcv = (float*)p; p += 32 * N * 4;
    float* pct = (float*)p; p += 32 * N * 4;
    float* st1 = (float*)p; p += 4 * 32 * 512 * 4;
    float* st2 = (float*)p; p += 4 * 32 * 512 * 4;
    float* partials = (float*)p; p += 64 * 10 * 4;
    float* stdpart  = (float*)p; p += 32 * 4;
    unsigned int* counter = (unsigned int*)p; p += 16;

    // 1. prep: normalize+split | diagonals | std partials (one dispatch)
    k_prep<<<dim3(6272), 256, 0, stream>>>(
        (const float*)d_in[0], (const float*)d_in[1],
        (const float*)d_in[2], (const float*)d_in[3],
        hiA[0], mat_stride, dv, dt, st1, st2, counter);

    // 2. both fused GEMMs in one dispatch (z selects)
    k_gemm<<<dim3(32, 32, 2), 256, 0, stream>>>(
        hiA[0], loA[0], hiA[1], loA[1], hiA[2], loA[2], hiA[3], loA[3],
        dv, dt, pev, pet, pcv, pct);

    // 3. finalization: rowred | colstd | last-block combine (one dispatch)
    k_fin<<<dim3(96), 64, 0, stream>>>(
        dv, dt, pev, pet, pcv, pct, st1, st2,
        partials, stdpart, counter, (float*)d_out);
}

// Round 6
// 213.983 us; speedup vs baseline: 1.1728x; 1.0141x over previous
//
#include <hip/hip_runtime.h>
#include <hip/hip_bf16.h>

#define N 4096
#define C 512

typedef __attribute__((ext_vector_type(8))) short bf16x8;
typedef __attribute__((ext_vector_type(8))) short s16x8;
typedef __attribute__((ext_vector_type(4))) float f32x4;

__device__ inline float bf2f(__hip_bfloat16 h) { return __bfloat162float(h); }

__device__ inline void gload16(const void* g, void* l) {
    __builtin_amdgcn_global_load_lds(
        (__attribute__((address_space(1))) void*)(g),
        (__attribute__((address_space(3))) void*)(l),
        16, 0, 0);
}

// ================= kernel 1: single-pass prep =================================
// 1024 blocks x 256 threads. Block b: matrix m=b>>8, chunk=b&255 (16 rows).
// Wave w owns rows chunk*16 + w*4 .. +3. Per row (ONE read of the fp32 row):
//   - norm reduce -> hi/lo bf16 split store
//   - per-column std partials accumulated in registers
//   - m==0/1: load partner row (pt/pv), fused ssb+dot reduce -> diagonal
// Block-level std partial -> st1/st2[(m*256+chunk)*512 + col].
__global__ __launch_bounds__(256) void k_prep(
    const float* __restrict__ s0, const float* __restrict__ s1f,
    const float* __restrict__ s2f, const float* __restrict__ s3,
    __hip_bfloat16* __restrict__ ws_hi0, long mat_stride,
    float* __restrict__ dv, float* __restrict__ dt,
    float* __restrict__ st1, float* __restrict__ st2,
    unsigned int* __restrict__ counter)
{
    __shared__ float sa[4][512];
    __shared__ float sq[4][512];

    const int b = blockIdx.x;
    const int tid = threadIdx.x;
    const int lane = tid & 63;
    const int w = tid >> 6;

    if (b == 0 && tid == 0) *counter = 0;

    const int m = b >> 8;
    const int chunk = b & 255;
    const float* src = (m == 0) ? s0 : (m == 1) ? s1f : (m == 2) ? s2f : s3;
    const float* srcB = (m == 0) ? s3 : s2f;      // pt for v, pv for t (m<2 only)
    float* dout = (m == 0) ? dv : dt;
    __hip_bfloat16* hi = ws_hi0 + (long)m * mat_stride;
    __hip_bfloat16* lo = hi + (long)N * C;

    float a[8], q[8];
    for (int e = 0; e < 8; e++) { a[e] = 0.f; q[e] = 0.f; }

    const int row0 = chunk * 16 + w * 4;
    for (int i = 0; i < 4; i++) {
        const int row = row0 + i;
        const float4* r4 = (const float4*)(src + (size_t)row * C);
        float4 x0 = r4[lane * 2];
        float4 x1 = r4[lane * 2 + 1];
        float ss = x0.x*x0.x + x0.y*x0.y + x0.z*x0.z + x0.w*x0.w
                 + x1.x*x1.x + x1.y*x1.y + x1.z*x1.z + x1.w*x1.w;
        for (int o = 1; o < 64; o <<= 1) ss += __shfl_xor(ss, o);
        float scale = 1.0f / fmaxf(sqrtf(ss), 1e-12f);

        float y[8] = { x0.x*scale, x0.y*scale, x0.z*scale, x0.w*scale,
                       x1.x*scale, x1.y*scale, x1.z*scale, x1.w*scale };
        __hip_bfloat16 hv[8], lv[8];
        for (int e = 0; e < 8; e++) {
            hv[e] = __float2bfloat16(y[e]);
            lv[e] = __float2bfloat16(y[e] - bf2f(hv[e]));
            a[e] += y[e];
            q[e] += y[e] * y[e];
        }
        size_t base = (size_t)row * C + lane * 8;
        *(s16x8*)(hi + base) = *(s16x8*)hv;
        *(s16x8*)(lo + base) = *(s16x8*)lv;

        if (m < 2) {
            const float4* b4 = (const float4*)(srcB + (size_t)row * C);
            float4 b0 = b4[lane * 2], b1 = b4[lane * 2 + 1];
            float ssb = b0.x*b0.x + b0.y*b0.y + b0.z*b0.z + b0.w*b0.w
                      + b1.x*b1.x + b1.y*b1.y + b1.z*b1.z + b1.w*b1.w;
            float dot = x0.x*b0.x + x0.y*b0.y + x0.z*b0.z + x0.w*b0.w
                      + x1.x*b1.x + x1.y*b1.y + x1.z*b1.z + x1.w*b1.w;
            for (int o = 1; o < 64; o <<= 1) {
                ssb += __shfl_xor(ssb, o);
                dot += __shfl_xor(dot, o);
            }
            if (lane == 0)
                dout[row] = dot * scale / fmaxf(sqrtf(ssb), 1e-12f);
        }
    }

    for (int e = 0; e < 8; e++) {
        sa[w][lane * 8 + e] = a[e];
        sq[w][lane * 8 + e] = q[e];
    }
    __syncthreads();
    for (int c = tid; c < 512; c += 256) {
        float A = sa[0][c] + sa[1][c] + sa[2][c] + sa[3][c];
        float B = sq[0][c] + sq[1][c] + sq[2][c] + sq[3][c];
        size_t o = ((size_t)m * 256 + chunk) * 512 + c;
        st1[o] = A;
        st2[o] = B;
    }
}

// ================= kernel 2: fused split-GEMM + epilogue (16x16x32) ===========
// C-tile 128x128, BK=32, 4 waves (2x2), 3 MFMA per frag pair (hi*hi+hi*lo+lo*hi).
// XOR k-block swizzle (round-5 verified: SQ_LDS_BANK_CONFLICT == 0).
__global__ __launch_bounds__(256) void k_gemm(
    const __hip_bfloat16* __restrict__ h0, const __hip_bfloat16* __restrict__ l0,
    const __hip_bfloat16* __restrict__ h1, const __hip_bfloat16* __restrict__ l1,
    const __hip_bfloat16* __restrict__ h2, const __hip_bfloat16* __restrict__ l2,
    const __hip_bfloat16* __restrict__ h3, const __hip_bfloat16* __restrict__ l3,
    const float* __restrict__ dv, const float* __restrict__ dt,
    float* __restrict__ pev, float* __restrict__ pet,
    float* __restrict__ pcv, float* __restrict__ pct)
{
    __shared__ __align__(16) __hip_bfloat16 sA[2][128][32];
    __shared__ __align__(16) __hip_bfloat16 sB[2][128][32];
    __shared__ float sdiag[128];
    __shared__ float sred[128][2][2];

    const int z = blockIdx.z;
    const __hip_bfloat16* Ah = z ? h1 : h0;
    const __hip_bfloat16* Al = z ? l1 : l0;
    const __hip_bfloat16* Bh = z ? h2 : h3;
    const __hip_bfloat16* Bl = z ? l2 : l3;
    const float* diag = z ? dt : dv;
    float* pe = z ? pet : pev;
    float* pc = z ? pct : pcv;

    const int tid = threadIdx.x;
    const int lane = tid & 63;
    const int w = tid >> 6;
    const int wy = w >> 1, wx = w & 1;
    const int bm = blockIdx.x * 128;
    const int bn = blockIdx.y * 128;

    if (tid < 128) sdiag[tid] = diag[bm + tid];

    f32x4 acc[4][4];
    for (int i = 0; i < 4; i++)
        for (int j = 0; j < 4; j++)
            acc[i][j] = (f32x4){0.f, 0.f, 0.f, 0.f};

    const int srow = lane >> 2;                               // 0..15
    const int lcol = (lane & 3) * 8;                          // LDS dst (natural)
    const int scolg = (((lane & 3) ^ ((lane >> 3) & 3))) * 8; // swizzled global k
    const int fr = lane & 15;
    const int pcs = ((lane >> 4) ^ ((fr >> 1) & 3)) * 8;      // swizzled read k

    for (int k0 = 0; k0 < C; k0 += 32) {
        for (int half = 0; half < 2; half++) {
            int rr = w * 16 + half * 64 + srow;
            size_t ga = (size_t)(bm + rr) * C + k0 + scolg;
            size_t gb = (size_t)(bn + rr) * C + k0 + scolg;
            gload16(Ah + ga, &sA[0][rr][lcol]);
            gload16(Al + ga, &sA[1][rr][lcol]);
            gload16(Bh + gb, &sB[0][rr][lcol]);
            gload16(Bl + gb, &sB[1][rr][lcol]);
        }
        __syncthreads();

        bf16x8 a_h[4], a_l[4], b_h[4], b_l[4];
        for (int i = 0; i < 4; i++) {
            a_h[i] = *(const bf16x8*)&sA[0][wy * 64 + i * 16 + fr][pcs];
            a_l[i] = *(const bf16x8*)&sA[1][wy * 64 + i * 16 + fr][pcs];
            b_h[i] = *(const bf16x8*)&sB[0][wx * 64 + i * 16 + fr][pcs];
            b_l[i] = *(const bf16x8*)&sB[1][wx * 64 + i * 16 + fr][pcs];
        }
        for (int i = 0; i < 4; i++)
            for (int j = 0; j < 4; j++) {
                acc[i][j] = __builtin_amdgcn_mfma_f32_16x16x32_bf16(a_h[i], b_h[j], acc[i][j], 0, 0, 0);
                acc[i][j] = __builtin_amdgcn_mfma_f32_16x16x32_bf16(a_h[i], b_l[j], acc[i][j], 0, 0, 0);
                acc[i][j] = __builtin_amdgcn_mfma_f32_16x16x32_bf16(a_l[i], b_h[j], acc[i][j], 0, 0, 0);
            }
        __syncthreads();
    }

    // epilogue: C/D layout row=(lane>>4)*4+reg, col=lane&15
    const int quad = lane >> 4;
    for (int i = 0; i < 4; i++) {
        for (int reg = 0; reg < 4; reg++) {
            int rloc = wy * 64 + i * 16 + quad * 4 + reg;
            int grow = bm + rloc;
            float d = sdiag[rloc];
            float e = 0.f, c = 0.f;
            for (int j = 0; j < 4; j++) {
                float s = acc[i][j][reg];
                int gcol = bn + wx * 64 + j * 16 + fr;
                e += __expf(10.f * s - 10.f);
                if (s > d && gcol != grow) c += 1.f;
            }
            for (int o = 1; o < 16; o <<= 1) {
                e += __shfl_xor(e, o);
                c += __shfl_xor(c, o);
            }
            if (fr == 0) { sred[rloc][wx][0] = e; sred[rloc][wx][1] = c; }
        }
    }
    __syncthreads();
    if (tid < 128) {
        size_t idx = (size_t)(bm + tid) * 32 + blockIdx.y;
        pe[idx] = sred[tid][0][0] + sred[tid][1][0];
        pc[idx] = sred[tid][0][1] + sred[tid][1][1];
    }
}

// ================= kernel 3: finalization (rowred | colstd | last-block) ======
__global__ __launch_bounds__(64) void k_fin(
    const float* __restrict__ dv, const float* __restrict__ dt,
    const float* __restrict__ pev, const float* __restrict__ pet,
    const float* __restrict__ pcv, const float* __restrict__ pct,
    const float* __restrict__ st1, const float* __restrict__ st2,
    float* __restrict__ partials, float* __restrict__ stdpart,
    unsigned int* __restrict__ counter, float* __restrict__ out)
{
    const int b = blockIdx.x;
    const int lane = threadIdx.x;

    if (b < 64) {
        const int row = b * 64 + lane;
        float se = 0.f, pv = 0.f, pt = 0.f;
        const float4* e4v = (const float4*)(pev + (size_t)row * 32);
        const float4* e4t = (const float4*)(pet + (size_t)row * 32);
        const float4* c4v = (const float4*)(pcv + (size_t)row * 32);
        const float4* c4t = (const float4*)(pct + (size_t)row * 32);
        for (int qd = 0; qd < 8; qd++) {
            float4 aa = e4v[qd], bb = e4t[qd], cc = c4v[qd], dd = c4t[qd];
            se += aa.x + aa.y + aa.z + aa.w + bb.x + bb.y + bb.z + bb.w;
            pv += cc.x + cc.y + cc.z + cc.w;
            pt += dd.x + dd.y + dd.z + dd.w;
        }
        float vals[10];
        vals[0] = logf(se) + 10.f;
        vals[1] = (pv < 0.5f) ? 1.f : 0.f;
        vals[2] = (pv < 4.5f) ? 1.f : 0.f;
        vals[3] = (pv < 9.5f) ? 1.f : 0.f;
        vals[4] = pv;
        vals[5] = (pt < 0.5f) ? 1.f : 0.f;
        vals[6] = (pt < 4.5f) ? 1.f : 0.f;
        vals[7] = (pt < 9.5f) ? 1.f : 0.f;
        vals[8] = pt;
        vals[9] = __expf(10.f * dv[row] - 10.f) + __expf(10.f * dt[row] - 10.f);
        for (int k = 0; k < 10; k++) {
            float v = vals[k];
            for (int o = 1; o < 64; o <<= 1) v += __shfl_xor(v, o);
            if (lane == k) partials[(size_t)b * 10 + k] = v;
        }
    } else {
        const int idx = b - 64;              // 0..31
        const int m = idx >> 3;
        const int col = (idx & 7) * 64 + lane;
        float a = 0.f, q = 0.f;
        for (int ch = 0; ch < 256; ch++) {
            size_t o = ((size_t)m * 256 + ch) * 512 + col;
            a += st1[o];
            q += st2[o];
        }
        float var = (q - a * a * (1.f / N)) * (1.f / (N - 1));
        float sd = sqrtf(fmaxf(var, 0.f));
        for (int o = 1; o < 64; o <<= 1) sd += __shfl_xor(sd, o);
        if (lane == 0) stdpart[idx] = sd;
    }

    __syncthreads();
    __shared__ unsigned int s_old;
    if (lane == 0) {
        __threadfence();                     // release our partial writes
        s_old = atomicAdd(counter, 1u);
    }
    __syncthreads();
    if (s_old != 95) return;
    __threadfence();                         // acquire everyone's writes

    // ---- last block: final combine (deterministic order) ----
    float v = 0.f;
    if (lane < 10) {
        for (int k = 0; k < 64; k++) v += partials[k * 10 + lane];
    }
    __shared__ float g[10];
    __shared__ float stds[4];
    if (lane < 10) g[lane] = v;
    if (lane < 4) {
        float s = 0.f;
        for (int i = 0; i < 8; i++) s += stdpart[lane * 8 + i];
        stds[lane] = s * (1.f / 512.f);
    }
    __syncthreads();
    if (lane == 0) {
        const float invN = 1.f / N;
        float nominator = logf(g[9]) + 10.f;
        out[0]  = g[0] * invN - nominator;
        out[1]  = stds[0];
        out[2]  = stds[1];
        out[3]  = stds[2];
        out[4]  = stds[3];
        out[5]  = g[1] * invN;
        out[6]  = g[2] * invN;
        out[7]  = g[3] * invN;
        out[8]  = g[4] * invN;
        out[9]  = g[5] * invN;
        out[10] = g[6] * invN;
        out[11] = g[7] * invN;
        out[12] = g[8] * invN;
    }
}

extern "C" void kernel_launch(void* const* d_in, const int* in_sizes, int n_in,
                              void* d_out, int out_size, void* d_ws, size_t ws_size,
                              hipStream_t stream)
{
    char* p = (char*)d_ws;
    const size_t NE = (size_t)N * C;           // 2,097,152 elems
    const long mat_stride = 2 * NE;            // hi + lo, in bf16 elems
    __hip_bfloat16* hiA[4];
    __hip_bfloat16* loA[4];
    for (int m = 0; m < 4; m++) {
        hiA[m] = (__hip_bfloat16*)p; p += NE * 2;
        loA[m] = (__hip_bfloat16*)p; p += NE * 2;
    }
    float* dv  = (float*)p; p += N * 4;
    float* dt  = (float*)p; p += N * 4;
    float* pev = (float*)p; p += 32 * N * 4;
    float* pet = (float*)p; p += 32 * N * 4;
    float* pcv = (float*)p; p += 32 * N * 4;
    float* pct = (float*)p; p += 32 * N * 4;
    float* st1 = (float*)p; p += 4 * 256 * 512 * 4;
    float* st2 = (float*)p; p += 4 * 256 * 512 * 4;
    float* partials = (float*)p; p += 64 * 10 * 4;
    float* stdpart  = (float*)p; p += 32 * 4;
    unsigned int* counter = (unsigned int*)p; p += 16;

    // 1. single-pass prep: norm+split + diag + std partials
    k_prep<<<dim3(1024), 256, 0, stream>>>(
        (const float*)d_in[0], (const float*)d_in[1],
        (const float*)d_in[2], (const float*)d_in[3],
        hiA[0], mat_stride, dv, dt, st1, st2, counter);

    // 2. both fused GEMMs in one dispatch (z selects)
    k_gemm<<<dim3(32, 32, 2), 256, 0, stream>>>(
        hiA[0], loA[0], hiA[1], loA[1], hiA[2], loA[2], hiA[3], loA[3],
        dv, dt, pev, pet, pcv, pct);

    // 3. finalization: rowred | colstd | last-block combine (one dispatch)
    k_fin<<<dim3(96), 64, 0, stream>>>(
        dv, dt, pev, pet, pcv, pct, st1, st2,
        partials, stdpart, counter, (float*)d_out);
}

// Round 7
// 213.104 us; speedup vs baseline: 1.1777x; 1.0041x over previous
//
#include <hip/hip_runtime.h>
#include <hip/hip_bf16.h>

#define N 4096
#define C 512

typedef __attribute__((ext_vector_type(8))) short bf16x8;
typedef __attribute__((ext_vector_type(8))) short s16x8;
typedef __attribute__((ext_vector_type(4))) float f32x4;

__device__ inline float bf2f(__hip_bfloat16 h) { return __bfloat162float(h); }

__device__ inline void gload16(const void* g, void* l) {
    __builtin_amdgcn_global_load_lds(
        (__attribute__((address_space(1))) void*)(g),
        (__attribute__((address_space(3))) void*)(l),
        16, 0, 0);
}

// ================= kernel 1: single-pass paired prep ==========================
// 512 blocks x 256 threads. pair = b>>8 (0: v&pt -> dv, 1: t&pv -> dt),
// chunk = b&255 (16 rows). Wave w owns rows chunk*16 + w*4 .. +3.
// Per row-pair (ONE read of each fp32 row):
//   - interleaved 3-chain shuffle reduce (|x|^2, |b|^2, x.b)
//   - hi/lo bf16 split store for BOTH matrices
//   - diagonal dv/dt
//   - per-column std partials for both matrices -> atomicAdd into colsum/colsq
__global__ __launch_bounds__(256) void k_prep(
    const float* __restrict__ s0, const float* __restrict__ s1f,
    const float* __restrict__ s2f, const float* __restrict__ s3,
    __hip_bfloat16* __restrict__ ws_hi0, long mat_stride,
    float* __restrict__ dv, float* __restrict__ dt,
    float* __restrict__ colsum, float* __restrict__ colsq)
{
    __shared__ float sa[4][512];
    __shared__ float sq[4][512];

    const int b = blockIdx.x;
    const int tid = threadIdx.x;
    const int lane = tid & 63;
    const int w = tid >> 6;

    const int pair = b >> 8;
    const int chunk = b & 255;
    const float* X = pair ? s1f : s0;        // t : v
    const float* B = pair ? s2f : s3;        // pv : pt
    const int mX = pair ? 1 : 0;
    const int mB = pair ? 2 : 3;
    __hip_bfloat16* hiX = ws_hi0 + (long)mX * mat_stride;
    __hip_bfloat16* loX = hiX + (long)N * C;
    __hip_bfloat16* hiB = ws_hi0 + (long)mB * mat_stride;
    __hip_bfloat16* loB = hiB + (long)N * C;
    float* dout = pair ? dt : dv;

    float aX[8], qX[8], aB[8], qB[8];
    for (int e = 0; e < 8; e++) { aX[e] = 0.f; qX[e] = 0.f; aB[e] = 0.f; qB[e] = 0.f; }

    const int row0 = chunk * 16 + w * 4;
    for (int i = 0; i < 4; i++) {
        const int row = row0 + i;
        const float4* x4 = (const float4*)(X + (size_t)row * C);
        const float4* b4 = (const float4*)(B + (size_t)row * C);
        float4 x0 = x4[lane * 2], x1 = x4[lane * 2 + 1];
        float4 b0 = b4[lane * 2], b1 = b4[lane * 2 + 1];

        float ss  = x0.x*x0.x + x0.y*x0.y + x0.z*x0.z + x0.w*x0.w
                  + x1.x*x1.x + x1.y*x1.y + x1.z*x1.z + x1.w*x1.w;
        float ssb = b0.x*b0.x + b0.y*b0.y + b0.z*b0.z + b0.w*b0.w
                  + b1.x*b1.x + b1.y*b1.y + b1.z*b1.z + b1.w*b1.w;
        float dot = x0.x*b0.x + x0.y*b0.y + x0.z*b0.z + x0.w*b0.w
                  + x1.x*b1.x + x1.y*b1.y + x1.z*b1.z + x1.w*b1.w;
        for (int o = 1; o < 64; o <<= 1) {       // 3 independent chains, interleaved
            ss  += __shfl_xor(ss, o);
            ssb += __shfl_xor(ssb, o);
            dot += __shfl_xor(dot, o);
        }
        float scX = 1.0f / fmaxf(sqrtf(ss), 1e-12f);
        float scB = 1.0f / fmaxf(sqrtf(ssb), 1e-12f);
        if (lane == 0) dout[row] = dot * scX * scB;

        float yx[8] = { x0.x*scX, x0.y*scX, x0.z*scX, x0.w*scX,
                        x1.x*scX, x1.y*scX, x1.z*scX, x1.w*scX };
        float yb[8] = { b0.x*scB, b0.y*scB, b0.z*scB, b0.w*scB,
                        b1.x*scB, b1.y*scB, b1.z*scB, b1.w*scB };
        __hip_bfloat16 hvx[8], lvx[8], hvb[8], lvb[8];
        for (int e = 0; e < 8; e++) {
            hvx[e] = __float2bfloat16(yx[e]);
            lvx[e] = __float2bfloat16(yx[e] - bf2f(hvx[e]));
            aX[e] += yx[e]; qX[e] += yx[e] * yx[e];
            hvb[e] = __float2bfloat16(yb[e]);
            lvb[e] = __float2bfloat16(yb[e] - bf2f(hvb[e]));
            aB[e] += yb[e]; qB[e] += yb[e] * yb[e];
        }
        size_t base = (size_t)row * C + lane * 8;
        *(s16x8*)(hiX + base) = *(s16x8*)hvx;
        *(s16x8*)(loX + base) = *(s16x8*)lvx;
        *(s16x8*)(hiB + base) = *(s16x8*)hvb;
        *(s16x8*)(loB + base) = *(s16x8*)lvb;
    }

    // std partials: two LDS rounds (X then B), atomicAdd into colsum/colsq
    for (int e = 0; e < 8; e++) { sa[w][lane*8+e] = aX[e]; sq[w][lane*8+e] = qX[e]; }
    __syncthreads();
    for (int c = tid; c < 512; c += 256) {
        atomicAdd(&colsum[mX * 512 + c], sa[0][c] + sa[1][c] + sa[2][c] + sa[3][c]);
        atomicAdd(&colsq [mX * 512 + c], sq[0][c] + sq[1][c] + sq[2][c] + sq[3][c]);
    }
    __syncthreads();
    for (int e = 0; e < 8; e++) { sa[w][lane*8+e] = aB[e]; sq[w][lane*8+e] = qB[e]; }
    __syncthreads();
    for (int c = tid; c < 512; c += 256) {
        atomicAdd(&colsum[mB * 512 + c], sa[0][c] + sa[1][c] + sa[2][c] + sa[3][c]);
        atomicAdd(&colsq [mB * 512 + c], sq[0][c] + sq[1][c] + sq[2][c] + sq[3][c]);
    }
}

// ================= kernel 2: fused split-GEMM + atomic epilogue ===============
// C-tile 128x128, BK=32, 4 waves (2x2), 3 MFMA per frag pair.
// XOR k-block swizzle (round-5 verified: SQ_LDS_BANK_CONFLICT == 0).
// Epilogue: per-row e/c partials -> atomicAdd into row_e/row_c (z-selected).
// Counts are integer-valued fp32 (<2^24) => order-exact; exp-sum order noise
// ~1e-7 rel, far below the 2% loss threshold.
__global__ __launch_bounds__(256) void k_gemm(
    const __hip_bfloat16* __restrict__ h0, const __hip_bfloat16* __restrict__ l0,
    const __hip_bfloat16* __restrict__ h1, const __hip_bfloat16* __restrict__ l1,
    const __hip_bfloat16* __restrict__ h2, const __hip_bfloat16* __restrict__ l2,
    const __hip_bfloat16* __restrict__ h3, const __hip_bfloat16* __restrict__ l3,
    const float* __restrict__ dv, const float* __restrict__ dt,
    float* __restrict__ row_ev, float* __restrict__ row_et,
    float* __restrict__ row_cv, float* __restrict__ row_ct)
{
    __shared__ __align__(16) __hip_bfloat16 sA[2][128][32];
    __shared__ __align__(16) __hip_bfloat16 sB[2][128][32];
    __shared__ float sdiag[128];
    __shared__ float sred[128][2][2];

    const int z = blockIdx.z;
    const __hip_bfloat16* Ah = z ? h1 : h0;
    const __hip_bfloat16* Al = z ? l1 : l0;
    const __hip_bfloat16* Bh = z ? h2 : h3;
    const __hip_bfloat16* Bl = z ? l2 : l3;
    const float* diag = z ? dt : dv;
    float* row_e = z ? row_et : row_ev;
    float* row_c = z ? row_ct : row_cv;

    const int tid = threadIdx.x;
    const int lane = tid & 63;
    const int w = tid >> 6;
    const int wy = w >> 1, wx = w & 1;
    const int bm = blockIdx.x * 128;
    const int bn = blockIdx.y * 128;

    if (tid < 128) sdiag[tid] = diag[bm + tid];

    f32x4 acc[4][4];
    for (int i = 0; i < 4; i++)
        for (int j = 0; j < 4; j++)
            acc[i][j] = (f32x4){0.f, 0.f, 0.f, 0.f};

    const int srow = lane >> 2;                               // 0..15
    const int lcol = (lane & 3) * 8;                          // LDS dst (natural)
    const int scolg = (((lane & 3) ^ ((lane >> 3) & 3))) * 8; // swizzled global k
    const int fr = lane & 15;
    const int pcs = ((lane >> 4) ^ ((fr >> 1) & 3)) * 8;      // swizzled read k

    for (int k0 = 0; k0 < C; k0 += 32) {
        for (int half = 0; half < 2; half++) {
            int rr = w * 16 + half * 64 + srow;
            size_t ga = (size_t)(bm + rr) * C + k0 + scolg;
            size_t gb = (size_t)(bn + rr) * C + k0 + scolg;
            gload16(Ah + ga, &sA[0][rr][lcol]);
            gload16(Al + ga, &sA[1][rr][lcol]);
            gload16(Bh + gb, &sB[0][rr][lcol]);
            gload16(Bl + gb, &sB[1][rr][lcol]);
        }
        __syncthreads();

        bf16x8 a_h[4], a_l[4], b_h[4], b_l[4];
        for (int i = 0; i < 4; i++) {
            a_h[i] = *(const bf16x8*)&sA[0][wy * 64 + i * 16 + fr][pcs];
            a_l[i] = *(const bf16x8*)&sA[1][wy * 64 + i * 16 + fr][pcs];
            b_h[i] = *(const bf16x8*)&sB[0][wx * 64 + i * 16 + fr][pcs];
            b_l[i] = *(const bf16x8*)&sB[1][wx * 64 + i * 16 + fr][pcs];
        }
        for (int i = 0; i < 4; i++)
            for (int j = 0; j < 4; j++) {
                acc[i][j] = __builtin_amdgcn_mfma_f32_16x16x32_bf16(a_h[i], b_h[j], acc[i][j], 0, 0, 0);
                acc[i][j] = __builtin_amdgcn_mfma_f32_16x16x32_bf16(a_h[i], b_l[j], acc[i][j], 0, 0, 0);
                acc[i][j] = __builtin_amdgcn_mfma_f32_16x16x32_bf16(a_l[i], b_h[j], acc[i][j], 0, 0, 0);
            }
        __syncthreads();
    }

    // epilogue: C/D layout row=(lane>>4)*4+reg, col=lane&15
    const int quad = lane >> 4;
    for (int i = 0; i < 4; i++) {
        for (int reg = 0; reg < 4; reg++) {
            int rloc = wy * 64 + i * 16 + quad * 4 + reg;
            int grow = bm + rloc;
            float d = sdiag[rloc];
            float e = 0.f, c = 0.f;
            for (int j = 0; j < 4; j++) {
                float s = acc[i][j][reg];
                int gcol = bn + wx * 64 + j * 16 + fr;
                e += __expf(10.f * s - 10.f);
                if (s > d && gcol != grow) c += 1.f;
            }
            for (int o = 1; o < 16; o <<= 1) {
                e += __shfl_xor(e, o);
                c += __shfl_xor(c, o);
            }
            if (fr == 0) { sred[rloc][wx][0] = e; sred[rloc][wx][1] = c; }
        }
    }
    __syncthreads();
    if (tid < 128) {
        atomicAdd(&row_e[bm + tid], sred[tid][0][0] + sred[tid][1][0]);
        atomicAdd(&row_c[bm + tid], sred[tid][0][1] + sred[tid][1][1]);
    }
}

// ================= kernel 3: tiny finalization (1 block, 96 KB of L2-hot reads)
__global__ __launch_bounds__(256) void k_fin(
    const float* __restrict__ dv, const float* __restrict__ dt,
    const float* __restrict__ row_ev, const float* __restrict__ row_et,
    const float* __restrict__ row_cv, const float* __restrict__ row_ct,
    const float* __restrict__ colsum, const float* __restrict__ colsq,
    float* __restrict__ out)
{
    const int t = threadIdx.x;
    const int lane = t & 63;
    const int wv = t >> 6;

    float vals[10];
    for (int k = 0; k < 10; k++) vals[k] = 0.f;
    for (int i = 0; i < 16; i++) {
        const int row = i * 256 + t;
        float se = row_ev[row] + row_et[row];
        float pv = row_cv[row];
        float pt = row_ct[row];
        vals[0] += logf(se) + 10.f;
        vals[1] += (pv < 0.5f) ? 1.f : 0.f;
        vals[2] += (pv < 4.5f) ? 1.f : 0.f;
        vals[3] += (pv < 9.5f) ? 1.f : 0.f;
        vals[4] += pv;
        vals[5] += (pt < 0.5f) ? 1.f : 0.f;
        vals[6] += (pt < 4.5f) ? 1.f : 0.f;
        vals[7] += (pt < 9.5f) ? 1.f : 0.f;
        vals[8] += pt;
        vals[9] += __expf(10.f * dv[row] - 10.f) + __expf(10.f * dt[row] - 10.f);
    }
    __shared__ float red[4][10];
    for (int k = 0; k < 10; k++) {
        float v = vals[k];
        for (int o = 1; o < 64; o <<= 1) v += __shfl_xor(v, o);
        if (lane == 0) red[wv][k] = v;
    }

    // stds: each thread handles cols t and t+256 of each matrix
    __shared__ float smat[4][4];
    for (int m = 0; m < 4; m++) {
        float sd2 = 0.f;
        for (int h = 0; h < 2; h++) {
            int c = h * 256 + t;
            float a = colsum[m * 512 + c];
            float q = colsq [m * 512 + c];
            float var = (q - a * a * (1.f / N)) * (1.f / (N - 1));
            sd2 += sqrtf(fmaxf(var, 0.f));
        }
        for (int o = 1; o < 64; o <<= 1) sd2 += __shfl_xor(sd2, o);
        if (lane == 0) smat[wv][m] = sd2;
    }
    __syncthreads();
    if (t == 0) {
        float g[10];
        for (int k = 0; k < 10; k++)
            g[k] = red[0][k] + red[1][k] + red[2][k] + red[3][k];
        float stds[4];
        for (int m = 0; m < 4; m++)
            stds[m] = (smat[0][m] + smat[1][m] + smat[2][m] + smat[3][m]) * (1.f / 512.f);
        const float invN = 1.f / N;
        float nominator = logf(g[9]) + 10.f;
        out[0]  = g[0] * invN - nominator;
        out[1]  = stds[0];
        out[2]  = stds[1];
        out[3]  = stds[2];
        out[4]  = stds[3];
        out[5]  = g[1] * invN;
        out[6]  = g[2] * invN;
        out[7]  = g[3] * invN;
        out[8]  = g[4] * invN;
        out[9]  = g[5] * invN;
        out[10] = g[6] * invN;
        out[11] = g[7] * invN;
        out[12] = g[8] * invN;
    }
}

extern "C" void kernel_launch(void* const* d_in, const int* in_sizes, int n_in,
                              void* d_out, int out_size, void* d_ws, size_t ws_size,
                              hipStream_t stream)
{
    char* p = (char*)d_ws;

    // --- zeroed accumulator region (contiguous, 80 KB) ---
    float* row_ev = (float*)p; p += N * 4;
    float* row_et = (float*)p; p += N * 4;
    float* row_cv = (float*)p; p += N * 4;
    float* row_ct = (float*)p; p += N * 4;
    float* colsum = (float*)p; p += 4 * 512 * 4;
    float* colsq  = (float*)p; p += 4 * 512 * 4;
    const size_t acc_bytes = (size_t)(p - (char*)d_ws);

    // --- plain workspace ---
    const size_t NE = (size_t)N * C;           // 2,097,152 elems
    const long mat_stride = 2 * NE;            // hi + lo, in bf16 elems
    __hip_bfloat16* hiA[4];
    __hip_bfloat16* loA[4];
    for (int m = 0; m < 4; m++) {
        hiA[m] = (__hip_bfloat16*)p; p += NE * 2;
        loA[m] = (__hip_bfloat16*)p; p += NE * 2;
    }
    float* dv = (float*)p; p += N * 4;
    float* dt = (float*)p; p += N * 4;

    hipMemsetAsync(d_ws, 0, acc_bytes, stream);

    // 1. paired single-pass prep: split x4 + diag + col-std atomics
    k_prep<<<dim3(512), 256, 0, stream>>>(
        (const float*)d_in[0], (const float*)d_in[1],
        (const float*)d_in[2], (const float*)d_in[3],
        hiA[0], mat_stride, dv, dt, colsum, colsq);

    // 2. both fused GEMMs in one dispatch (z selects), atomic row epilogue
    k_gemm<<<dim3(32, 32, 2), 256, 0, stream>>>(
        hiA[0], loA[0], hiA[1], loA[1], hiA[2], loA[2], hiA[3], loA[3],
        dv, dt, row_ev, row_et, row_cv, row_ct);

    // 3. tiny finalization (single block; inputs are L2-hot)
    k_fin<<<dim3(1), 256, 0, stream>>>(
        dv, dt, row_ev, row_et, row_cv, row_ct, colsum, colsq, (float*)d_out);
}